// Round 6
// baseline (2185.624 us; speedup 1.0000x reference)
//
#include <hip/hip_runtime.h>
#include <math.h>

#define N_B 16
#define T_LEN 4096

typedef double vdouble4 __attribute__((ext_vector_type(4)));

// ---- workspace layout (float offsets) — identical to round 4 (proven fit) ----
static const size_t OFF_A    = 0;            // 16*128*4096 (enc h1 / dec h2)
static const size_t OFF_B    = 8388608;      // 16*256*4096 (enc h2 / dec h1)
static const size_t OFF_Z    = 25165824;     // 16*64*4096  (z, aliased by quantized)
static const size_t OFF_WT1  = 29360128;     // 30720
static const size_t OFF_WT2  = 29390848;     // 98304
static const size_t OFF_WT3  = 29489152;     // 16384
static const size_t OFF_WD1  = 29505536;     // 49152
static const size_t OFF_WD2  = 29554688;     // 98304
static const size_t OFF_WD3  = 29652992;     // 30720
static const size_t OFF_C2   = 29683712;     // 512 floats (f32-rounded |c|^2)
static const size_t OFF_ST   = 29684736;     // 256 double2
static const size_t OFF_LOSS = 29685760;     // 1 double

// ---- weight transpose helper: w[CO][CI][KS] -> wT[KS][CI][CO] (f32) ----
template<int C_OUT, int C_IN, int KS>
__device__ inline void tw(const float* __restrict__ w, float* __restrict__ wT, int e) {
    int co  = e / (C_IN * KS);
    int rem = e - co * (C_IN * KS);
    int ci  = rem / KS;
    int k   = rem - ci * KS;
    wT[(k * C_IN + ci) * C_OUT + co] = w[e];
}

// ---- prep: transpose all 6 weights (f32), codebook row norms (f64->f32), zero loss ----
__global__ __launch_bounds__(256) void prep_k(
        const float* __restrict__ w1, const float* __restrict__ w2,
        const float* __restrict__ w3, const float* __restrict__ wd1,
        const float* __restrict__ wd2, const float* __restrict__ wd3,
        const float* __restrict__ cb, float* wsf) {
    int e = blockIdx.x * 256 + threadIdx.x;
    if (e < 30720)        tw<128,  80, 3>(w1,  wsf + OFF_WT1, e);
    else if (e < 129024)  tw<256, 128, 3>(w2,  wsf + OFF_WT2, e - 30720);
    else if (e < 145408)  tw< 64, 256, 1>(w3,  wsf + OFF_WT3, e - 129024);
    else if (e < 194560)  tw<256,  64, 3>(wd1, wsf + OFF_WD1, e - 145408);
    else if (e < 292864)  tw<128, 256, 3>(wd2, wsf + OFF_WD2, e - 194560);
    else if (e < 323584)  tw< 80, 128, 3>(wd3, wsf + OFF_WD3, e - 292864);
    else if (e < 324096) {
        int c = e - 323584;
        const float* p = cb + (size_t)c * 64;
        double s = 0.0;
        for (int d = 0; d < 64; ++d) { double v = p[d]; s += v * v; }
        wsf[OFF_C2 + c] = (float)s;   // f32-rounded |c|^2, as the f32 ref has
    } else if (e == 324096) {
        *(double*)(wsf + OFF_LOSS) = 0.0;
    }
}

// ---- encoder conv1d via f64 MFMA implicit GEMM, with layout self-probe ----
// M=co, N=t, K=ci*ks. Block: 64t x 64co, 4 waves; wave w: co strip w*16,
// 4 t-tiles of 16. Assumed mfma_f64_16x16x4 layouts: A[m=lane&15][k=lane>>4],
// B[k=lane>>4][n=lane&15], D[row=(lane>>4)*4+i][col=lane&15]. If the probe
// detects any deviation, a layout-independent VALU f64 path computes the
// identical result (bit-exact under the f64-exact/f32-store contract).
template<int C_IN, int C_OUT, int KS, bool BN_IN>
__global__ __launch_bounds__(256) void mconv_k(
        const float* __restrict__ x, const float* __restrict__ wT,
        const float* __restrict__ bias, const double2* __restrict__ stats,
        float* __restrict__ out) {
    constexpr int CI_CH = (KS == 3) ? 16 : 32;
    constexpr int XCOLS = 64 + KS - 1;        // 66 or 64
    constexpr int XROW  = XCOLS + 2;          // bank stagger
    constexpr int WROW  = 66;                 // 64 + pad

    __shared__ __align__(16) double xs[CI_CH * XROW];
    __shared__ __align__(16) double ws[KS * CI_CH * WROW];
    __shared__ int okf;

    const int tid  = threadIdx.x;
    const int lane = tid & 63;
    const int wv   = tid >> 6;        // wave 0..3 -> co strip
    const int tn   = lane & 15;
    const int kq   = lane >> 4;

    const int n   = blockIdx.x >> 6;
    const int t0  = (blockIdx.x & 63) * 64;
    const int co0 = blockIdx.y * 64;

    // ---- layout self-probe (asymmetric integer operands, exact in f64) ----
    if (tid == 0) okf = 1;
    __syncthreads();
    {
        vdouble4 p = {0.0, 0.0, 0.0, 0.0};
        p = __builtin_amdgcn_mfma_f64_16x16x4f64(
                (double)lane, (double)(2 * lane + 5), p, 0, 0, 0);
        bool lok = true;
#pragma unroll
        for (int i = 0; i < 4; ++i) {
            int m = kq * 4 + i;
            double e = (double)(8 * m * tn + 212 * m + 192 * tn + 7648);
            lok = lok && (p[i] == e);
        }
        if (!lok) okf = 0;
    }
    __syncthreads();
    const bool okp = (okf != 0);

    vdouble4 acc[4];
#pragma unroll
    for (int tt = 0; tt < 4; ++tt)
#pragma unroll
        for (int i = 0; i < 4; ++i) acc[tt][i] = 0.0;

    for (int ci0 = 0; ci0 < C_IN; ci0 += CI_CH) {
        __syncthreads();
        // stage x tile as f64 (BN+ReLU of previous layer fused, f64; pad = 0)
        for (int e = tid; e < CI_CH * XCOLS; e += 256) {
            int ci  = e / XCOLS;
            int ttx = e - ci * XCOLS;
            int gt  = t0 + ttx - (KS / 2);
            double v = 0.0;
            if (gt >= 0 && gt < T_LEN) {
                float f = x[((size_t)(n * C_IN + ci0 + ci)) * T_LEN + gt];
                if (BN_IN) {
                    double2 s = stats[ci0 + ci];
                    v = fmax(fma((double)f, s.x, s.y), 0.0);
                } else v = (double)f;
            }
            xs[ci * XROW + ttx] = v;
        }
        // stage w tile, converting f32 -> f64 ([k][ci][co] contiguous in co)
        for (int e = tid; e < KS * CI_CH * 64; e += 256) {
            int r  = e >> 6;
            int co = e & 63;
            int k  = r / CI_CH;
            int ci = r - k * CI_CH;
            ws[(k * CI_CH + ci) * WROW + co] =
                (double)wT[((size_t)(k * C_IN + ci0 + ci)) * C_OUT + co0 + co];
        }
        __syncthreads();

        if (okp) {
#pragma unroll
            for (int k = 0; k < KS; ++k) {
#pragma unroll
                for (int c4 = 0; c4 < CI_CH / 4; ++c4) {
                    double av = ws[(k * CI_CH + c4 * 4 + kq) * WROW + wv * 16 + tn];
                    const double* xrow = &xs[(c4 * 4 + kq) * XROW + k + tn];
#pragma unroll
                    for (int tt = 0; tt < 4; ++tt) {
                        double bv = xrow[tt * 16];
                        acc[tt] = __builtin_amdgcn_mfma_f64_16x16x4f64(
                            av, bv, acc[tt], 0, 0, 0);
                    }
                }
            }
        } else {
            // layout-independent f64 fallback (same LDS tiles, same mapping)
            for (int k = 0; k < KS; ++k)
                for (int ci = 0; ci < CI_CH; ++ci) {
                    double wr[4], xr[4];
#pragma unroll
                    for (int i = 0; i < 4; ++i)
                        wr[i] = ws[(k * CI_CH + ci) * WROW + wv * 16 + kq * 4 + i];
#pragma unroll
                    for (int tt = 0; tt < 4; ++tt)
                        xr[tt] = xs[ci * XROW + k + tt * 16 + tn];
#pragma unroll
                    for (int tt = 0; tt < 4; ++tt)
#pragma unroll
                        for (int i = 0; i < 4; ++i)
                            acc[tt][i] = fma(wr[i], xr[tt], acc[tt][i]);
                }
        }
    }

    // epilogue: lane holds D[co = co0+wv*16+kq*4+i][t = t0+tt*16+tn]
#pragma unroll
    for (int tt = 0; tt < 4; ++tt) {
#pragma unroll
        for (int i = 0; i < 4; ++i) {
            int co = co0 + wv * 16 + kq * 4 + i;
            double bv = (double)bias[co];
            out[((size_t)(n * C_OUT + co)) * T_LEN + t0 + tt * 16 + tn] =
                (float)(acc[tt][i] + bv);
        }
    }
}

// ---- generic conv1d (f32 or f64 acc; fused f64-BN+ReLU on input) ----
template<int C_IN, int C_OUT, int KS, bool BN_IN, typename ACC>
__global__ __launch_bounds__(256) void conv_k(
        const float* __restrict__ x, const float* __restrict__ wT,
        const float* __restrict__ bias, const double2* __restrict__ stats,
        float* __restrict__ out) {
    constexpr int T_TILE = 128;
    constexpr int CI_CH  = (KS == 3) ? 16 : 32;
    constexpr int CI_SH  = (KS == 3) ? 4 : 5;
    constexpr int XCOLS  = T_TILE + KS - 1;
    constexpr int XROW   = (KS == 3) ? 132 : 128;

    __shared__ __align__(16) float xs[CI_CH * XROW];
    __shared__ __align__(16) float ws[KS * CI_CH * 64];

    const int tid = threadIdx.x;
    const int tx  = tid & 15;
    const int ty  = tid >> 4;
    const int n    = blockIdx.x >> 5;
    const int t0   = (blockIdx.x & 31) * T_TILE;
    const int co0  = blockIdx.y * 64;

    ACC acc[4][8];
#pragma unroll
    for (int i = 0; i < 4; ++i)
#pragma unroll
        for (int j = 0; j < 8; ++j) acc[i][j] = (ACC)0;

    for (int ci0 = 0; ci0 < C_IN; ci0 += CI_CH) {
        __syncthreads();
        for (int e = tid; e < CI_CH * XCOLS; e += 256) {
            int ci = e / XCOLS;
            int tt = e - ci * XCOLS;
            int cig = ci0 + ci;
            int gt  = t0 + tt - (KS / 2);
            float v = 0.f;
            if (gt >= 0 && gt < T_LEN) {
                v = x[((size_t)(n * C_IN + cig)) * T_LEN + gt];
                if (BN_IN) {
                    double2 s = stats[cig];
                    double vv = fma((double)v, s.x, s.y);
                    v = (float)fmax(vv, 0.0);
                }
            }
            xs[ci * XROW + tt] = v;
        }
        for (int e = tid; e < KS * CI_CH * 64; e += 256) {
            int co = e & 63;
            int r  = e >> 6;
            int ci = r & (CI_CH - 1);
            int k  = r >> CI_SH;
            int cig = ci0 + ci, cog = co0 + co;
            float v = 0.f;
            if (cog < C_OUT)
                v = wT[((size_t)(k * C_IN + cig)) * C_OUT + cog];
            ws[(k * CI_CH + ci) * 64 + co] = v;
        }
        __syncthreads();

        for (int ci = 0; ci < CI_CH; ++ci) {
            ACC xv[10];
            {
                const float* xr = &xs[ci * XROW + tx * 8];
                float4 a0 = *(const float4*)&xr[0];
                float4 a1 = *(const float4*)&xr[4];
                xv[0] = (ACC)a0.x; xv[1] = (ACC)a0.y; xv[2] = (ACC)a0.z; xv[3] = (ACC)a0.w;
                xv[4] = (ACC)a1.x; xv[5] = (ACC)a1.y; xv[6] = (ACC)a1.z; xv[7] = (ACC)a1.w;
                if (KS == 3) {
                    float2 a2 = *(const float2*)&xr[8];
                    xv[8] = (ACC)a2.x; xv[9] = (ACC)a2.y;
                } else { xv[8] = (ACC)0; xv[9] = (ACC)0; }
            }
            ACC wa[KS][4];
#pragma unroll
            for (int k = 0; k < KS; ++k) {
                float4 wvv = *(const float4*)&ws[(k * CI_CH + ci) * 64 + ty * 4];
                wa[k][0] = (ACC)wvv.x; wa[k][1] = (ACC)wvv.y;
                wa[k][2] = (ACC)wvv.z; wa[k][3] = (ACC)wvv.w;
            }
#pragma unroll
            for (int k = 0; k < KS; ++k)
#pragma unroll
                for (int i = 0; i < 4; ++i)
#pragma unroll
                    for (int j = 0; j < 8; ++j)
                        acc[i][j] = fma(wa[k][i], xv[j + k], acc[i][j]);
        }
    }

    const size_t tb = (size_t)t0 + (size_t)tx * 8;
#pragma unroll
    for (int i = 0; i < 4; ++i) {
        int co = co0 + ty * 4 + i;
        if (co < C_OUT) {
            ACC bv = (ACC)bias[co];
            float* o = out + ((size_t)(n * C_OUT + co)) * T_LEN + tb;
            float r[8];
#pragma unroll
            for (int j = 0; j < 8; ++j) r[j] = (float)(acc[i][j] + bv);
            *(float4*)&o[0] = make_float4(r[0], r[1], r[2], r[3]);
            *(float4*)&o[4] = make_float4(r[4], r[5], r[6], r[7]);
        }
    }
}

// ---- BN stats stage 1: one block per (channel, batch) row -> partial sums ----
__global__ __launch_bounds__(256) void stats1_k(
        const float* __restrict__ y, int C, double2* __restrict__ part) {
    int c = blockIdx.x % C, n = blockIdx.x / C;
    int tid = threadIdx.x;
    const float* p = y + ((size_t)(n * C + c)) * T_LEN;
    double s1 = 0.0, s2 = 0.0;
    for (int t = tid; t < T_LEN; t += 256) {
        double v = p[t];
        s1 += v; s2 += v * v;
    }
    __shared__ double r1[256], r2[256];
    r1[tid] = s1; r2[tid] = s2;
    __syncthreads();
    for (int s = 128; s > 0; s >>= 1) {
        if (tid < s) { r1[tid] += r1[tid + s]; r2[tid] += r2[tid + s]; }
        __syncthreads();
    }
    if (tid == 0) part[(size_t)c * N_B + n] = make_double2(r1[0], r2[0]);
}

// ---- BN stats stage 2: deterministic combine -> (scale, shift) per channel ----
__global__ __launch_bounds__(256) void stats2_k(
        const double2* __restrict__ part, int C, const float* __restrict__ g,
        const float* __restrict__ b, double2* __restrict__ stats) {
    int c = blockIdx.x * 256 + threadIdx.x;
    if (c >= C) return;
    double s1 = 0.0, s2 = 0.0;
    for (int n = 0; n < N_B; ++n) {
        double2 v = part[(size_t)c * N_B + n];
        s1 += v.x; s2 += v.y;
    }
    double m   = s1 / 65536.0;
    double var = s2 / 65536.0 - m * m;
    double sc  = (double)g[c] / sqrt(var + 1e-5);
    stats[c] = make_double2(sc, (double)b[c] - m * sc);
}

// ---- VQ: replicate the reference's f32 d2 formula exactly ----
__global__ __launch_bounds__(256) void vq_k(
        const float* z, const float* __restrict__ cb,
        const float* __restrict__ c2, float* q,
        float* __restrict__ idx_out, double* __restrict__ loss) {
    __shared__ __align__(16) float zs[64 * 68];
    __shared__ __align__(16) float cs[64 * 68];
    __shared__ float  szf[64];
    __shared__ float  redS[64 * 16];
    __shared__ int    redI[64 * 16];
    __shared__ int    idxs[64];
    __shared__ double dred[256];

    const int tid = threadIdx.x;
    const int tx  = tid & 15, ty = tid >> 4;
    const int n   = blockIdx.x >> 6;
    const int t0  = (blockIdx.x & 63) * 64;

    for (int e = tid; e < 4096; e += 256) {
        int t = e & 63, d = e >> 6;
        zs[t * 68 + d] = z[((size_t)(n * 64 + d)) * T_LEN + t0 + t];
    }
    __syncthreads();
    if (tid < 64) {
        double s = 0.0;
        const float* zr = &zs[tid * 68];
        for (int d = 0; d < 64; ++d) { double v = zr[d]; s += v * v; }
        szf[tid] = (float)s;
    }

    float best[4];
    int bidx[4];
#pragma unroll
    for (int i = 0; i < 4; ++i) { best[i] = 3.0e38f; bidx[i] = 1 << 30; }

    for (int ch = 0; ch < 8; ++ch) {
        __syncthreads();
        for (int e = tid; e < 4096; e += 256) {
            int d = e & 63, c = e >> 6;
            cs[c * 68 + d] = cb[((size_t)(ch * 64 + c)) * 64 + d];
        }
        __syncthreads();

        double acc[4][4];
#pragma unroll
        for (int i = 0; i < 4; ++i)
#pragma unroll
            for (int j = 0; j < 4; ++j) acc[i][j] = 0.0;

        for (int d = 0; d < 64; d += 4) {
            float4 zv[4], cv[4];
#pragma unroll
            for (int i = 0; i < 4; ++i)
                zv[i] = *(const float4*)&zs[(tx + 16 * i) * 68 + d];
#pragma unroll
            for (int j = 0; j < 4; ++j)
                cv[j] = *(const float4*)&cs[(ty + 16 * j) * 68 + d];
#pragma unroll
            for (int i = 0; i < 4; ++i)
#pragma unroll
                for (int j = 0; j < 4; ++j) {
                    acc[i][j] = fma((double)zv[i].x, (double)cv[j].x, acc[i][j]);
                    acc[i][j] = fma((double)zv[i].y, (double)cv[j].y, acc[i][j]);
                    acc[i][j] = fma((double)zv[i].z, (double)cv[j].z, acc[i][j]);
                    acc[i][j] = fma((double)zv[i].w, (double)cv[j].w, acc[i][j]);
                }
        }
#pragma unroll
        for (int j = 0; j < 4; ++j) {
            int cg = ch * 64 + ty + 16 * j;
            float cc = c2[cg];
#pragma unroll
            for (int i = 0; i < 4; ++i) {
                float m32 = (float)acc[i][j];
                float A   = szf[tx + 16 * i] + cc;
                float s   = A - 2.0f * m32;
                if (s < best[i] || (s == best[i] && cg < bidx[i])) {
                    best[i] = s; bidx[i] = cg;
                }
            }
        }
    }
#pragma unroll
    for (int i = 0; i < 4; ++i) {
        redS[(tx + 16 * i) * 16 + ty] = best[i];
        redI[(tx + 16 * i) * 16 + ty] = bidx[i];
    }
    __syncthreads();

    if (tid < 64) {
        int t = tid;
        float bs = 3.0e38f; int bi = 1 << 30;
        for (int y2 = 0; y2 < 16; ++y2) {
            float v = redS[t * 16 + y2];
            int vi  = redI[t * 16 + y2];
            if (v < bs || (v == bs && vi < bi)) { bs = v; bi = vi; }
        }
        idxs[t] = bi;
        idx_out[(size_t)n * T_LEN + t0 + t] = (float)bi;
    }
    __syncthreads();

    {
        int g = tid >> 6, t = tid & 63;
        int bi = idxs[t];
        double ls = 0.0;
        for (int dd = 0; dd < 16; ++dd) {
            int d = g * 16 + dd;
            float qv = cb[(size_t)bi * 64 + d];
            float zv = zs[t * 68 + d];
            double df = (double)qv - (double)zv;
            ls += df * df;
            q[((size_t)(n * 64 + d)) * T_LEN + t0 + t] = qv;
        }
        dred[tid] = ls;
    }
    __syncthreads();
    for (int s = 128; s > 0; s >>= 1) {
        if (tid < s) dred[tid] += dred[tid + s];
        __syncthreads();
    }
    if (tid == 0) atomicAdd(loss, dred[0]);
}

__global__ void fin_k(const double* __restrict__ loss, float* __restrict__ out) {
    if (threadIdx.x == 0 && blockIdx.x == 0)
        out[0] = (float)(1.25 * (*loss) / 4194304.0);
}

extern "C" void kernel_launch(void* const* d_in, const int* in_sizes, int n_in,
                              void* d_out, int out_size, void* d_ws, size_t ws_size,
                              hipStream_t stream) {
    const float* x      = (const float*)d_in[0];
    const float* enc_w1 = (const float*)d_in[1];
    const float* enc_b1 = (const float*)d_in[2];
    const float* bn1_g  = (const float*)d_in[3];
    const float* bn1_b  = (const float*)d_in[4];
    const float* enc_w2 = (const float*)d_in[5];
    const float* enc_b2 = (const float*)d_in[6];
    const float* bn2_g  = (const float*)d_in[7];
    const float* bn2_b  = (const float*)d_in[8];
    const float* enc_w3 = (const float*)d_in[9];
    const float* enc_b3 = (const float*)d_in[10];
    const float* cb     = (const float*)d_in[11];
    const float* dec_w1 = (const float*)d_in[12];
    const float* dec_b1 = (const float*)d_in[13];
    const float* dbn1_g = (const float*)d_in[14];
    const float* dbn1_b = (const float*)d_in[15];
    const float* dec_w2 = (const float*)d_in[16];
    const float* dec_b2 = (const float*)d_in[17];
    const float* dbn2_g = (const float*)d_in[18];
    const float* dbn2_b = (const float*)d_in[19];
    const float* dec_w3 = (const float*)d_in[20];
    const float* dec_b3 = (const float*)d_in[21];

    float* wsf   = (float*)d_ws;
    float* outf  = (float*)d_out;
    float* A     = wsf + OFF_A;
    float* Bb    = wsf + OFF_B;
    float* Z     = wsf + OFF_Z;
    double2* st  = (double2*)(wsf + OFF_ST);
    double* lossp = (double*)(wsf + OFF_LOSS);
    double2* partA = (double2*)A;
    double2* partB = (double2*)Bb;

    prep_k<<<1268, 256, 0, stream>>>(enc_w1, enc_w2, enc_w3,
                                     dec_w1, dec_w2, dec_w3, cb, wsf);

    // encoder: f64 MFMA implicit GEMM w/ self-probe + bit-exact VALU fallback
    mconv_k<80, 128, 3, false><<<dim3(1024, 2), 256, 0, stream>>>(
        x, wsf + OFF_WT1, enc_b1, nullptr, A);
    stats1_k<<<128 * N_B, 256, 0, stream>>>(A, 128, partB);
    stats2_k<<<1, 256, 0, stream>>>(partB, 128, bn1_g, bn1_b, st);
    mconv_k<128, 256, 3, true><<<dim3(1024, 4), 256, 0, stream>>>(
        A, wsf + OFF_WT2, enc_b2, st, Bb);
    stats1_k<<<256 * N_B, 256, 0, stream>>>(Bb, 256, partA);
    stats2_k<<<1, 256, 0, stream>>>(partA, 256, bn2_g, bn2_b, st);
    mconv_k<256, 64, 1, true><<<dim3(1024, 1), 256, 0, stream>>>(
        Bb, wsf + OFF_WT3, enc_b3, st, Z);

    // vector quantizer — f32-formula scores, exact ref grid
    vq_k<<<1024, 256, 0, stream>>>(Z, cb, wsf + OFF_C2, Z,
                                   outf + 5242881, lossp);
    fin_k<<<1, 64, 0, stream>>>(lossp, outf + 5242880);

    // decoder (f32 vector)
    conv_k<64, 256, 3, false, float><<<dim3(512, 4), 256, 0, stream>>>(
        Z, wsf + OFF_WD1, dec_b1, nullptr, Bb);
    stats1_k<<<256 * N_B, 256, 0, stream>>>(Bb, 256, partA);
    stats2_k<<<1, 256, 0, stream>>>(partA, 256, dbn1_g, dbn1_b, st);
    conv_k<256, 128, 3, true, float><<<dim3(512, 2), 256, 0, stream>>>(
        Bb, wsf + OFF_WD2, dec_b2, st, A);
    stats1_k<<<128 * N_B, 256, 0, stream>>>(A, 128, partB);
    stats2_k<<<1, 256, 0, stream>>>(partB, 128, dbn2_g, dbn2_b, st);
    conv_k<128, 80, 3, true, float><<<dim3(512, 2), 256, 0, stream>>>(
        A, wsf + OFF_WD3, dec_b3, st, outf);
}

// Round 7
// 1878.085 us; speedup vs baseline: 1.1638x; 1.1638x over previous
//
#include <hip/hip_runtime.h>
#include <math.h>

#define N_B 16
#define T_LEN 4096

typedef double vdouble4 __attribute__((ext_vector_type(4)));

// ---- workspace layout (float offsets) — identical to round 4 (proven fit) ----
static const size_t OFF_A    = 0;            // 16*128*4096 (enc h1 / dec h2)
static const size_t OFF_B    = 8388608;      // 16*256*4096 (enc h2 / dec h1)
static const size_t OFF_Z    = 25165824;     // 16*64*4096  (z, aliased by quantized)
static const size_t OFF_WT1  = 29360128;     // 30720
static const size_t OFF_WT2  = 29390848;     // 98304
static const size_t OFF_WT3  = 29489152;     // 16384
static const size_t OFF_WD1  = 29505536;     // 49152
static const size_t OFF_WD2  = 29554688;     // 98304
static const size_t OFF_WD3  = 29652992;     // 30720
static const size_t OFF_C2   = 29683712;     // 512 floats (f32-rounded |c|^2)
static const size_t OFF_ST   = 29684736;     // 256 double2
static const size_t OFF_LOSS = 29685760;     // 1 double

// ---- weight transpose helper: w[CO][CI][KS] -> wT[KS][CI][CO] (f32) ----
template<int C_OUT, int C_IN, int KS>
__device__ inline void tw(const float* __restrict__ w, float* __restrict__ wT, int e) {
    int co  = e / (C_IN * KS);
    int rem = e - co * (C_IN * KS);
    int ci  = rem / KS;
    int k   = rem - ci * KS;
    wT[(k * C_IN + ci) * C_OUT + co] = w[e];
}

// ---- prep: transpose all 6 weights (f32), codebook row norms (f64->f32), zero loss ----
__global__ __launch_bounds__(256) void prep_k(
        const float* __restrict__ w1, const float* __restrict__ w2,
        const float* __restrict__ w3, const float* __restrict__ wd1,
        const float* __restrict__ wd2, const float* __restrict__ wd3,
        const float* __restrict__ cb, float* wsf) {
    int e = blockIdx.x * 256 + threadIdx.x;
    if (e < 30720)        tw<128,  80, 3>(w1,  wsf + OFF_WT1, e);
    else if (e < 129024)  tw<256, 128, 3>(w2,  wsf + OFF_WT2, e - 30720);
    else if (e < 145408)  tw< 64, 256, 1>(w3,  wsf + OFF_WT3, e - 129024);
    else if (e < 194560)  tw<256,  64, 3>(wd1, wsf + OFF_WD1, e - 145408);
    else if (e < 292864)  tw<128, 256, 3>(wd2, wsf + OFF_WD2, e - 194560);
    else if (e < 323584)  tw< 80, 128, 3>(wd3, wsf + OFF_WD3, e - 292864);
    else if (e < 324096) {
        int c = e - 323584;
        const float* p = cb + (size_t)c * 64;
        double s = 0.0;
        for (int d = 0; d < 64; ++d) { double v = p[d]; s += v * v; }
        wsf[OFF_C2 + c] = (float)s;
    } else if (e == 324096) {
        *(double*)(wsf + OFF_LOSS) = 0.0;
    }
}

// ---- encoder conv1d via f64 MFMA implicit GEMM with LAYOUT DECODER probe ----
// M=co, N=t, K=ci*ks. Block: 64t x 64co, 4 waves; wave wv owns co strip wv*16.
// Probe decodes the hardware lane->fragment maps of mfma_f64_16x16x4 at
// runtime (P1: A=lane,B=1; P2: A=1,B=lane; P3 verify). On any mismatch a
// layout-independent VALU f64 path produces the identical result.
template<int C_IN, int C_OUT, int KS, bool BN_IN>
__global__ __launch_bounds__(256) void mconv_k(
        const float* __restrict__ x, const float* __restrict__ wT,
        const float* __restrict__ bias, const double2* __restrict__ stats,
        float* __restrict__ out) {
    constexpr int CI_CH = (KS == 3) ? 16 : 32;
    constexpr int XCOLS = 64 + KS - 1;
    constexpr int XROW  = XCOLS + 2;
    constexpr int WROW  = 66;

    __shared__ __align__(16) double xs[CI_CH * XROW];
    __shared__ __align__(16) double ws[KS * CI_CH * WROW];
    __shared__ int okf;

    const int tid  = threadIdx.x;
    const int lane = tid & 63;
    const int wv   = tid >> 6;
    const int tn   = lane & 15;
    const int kq   = lane >> 4;

    const int n   = blockIdx.x >> 6;
    const int t0  = (blockIdx.x & 63) * 64;
    const int co0 = blockIdx.y * 64;

    // ---- decode probe ----
    bool ok = true;
    int varA = 0, varB = 0;
    int dm[4], dnr[4];
    {
        vdouble4 p1 = {0.0, 0.0, 0.0, 0.0};
        p1 = __builtin_amdgcn_mfma_f64_16x16x4f64((double)lane, 1.0, p1, 0, 0, 0);
        {
            int iv = (int)p1[0];
            if (iv >= 96 && iv <= 156 && ((iv - 96) & 3) == 0) varA = 1;
            else if (iv >= 6 && iv <= 246 && ((iv - 6) & 15) == 0) varA = 2;
            else ok = false;
        }
#pragma unroll
        for (int r = 0; r < 4; ++r) {
            int iv = (int)p1[r];
            int m  = (varA == 2) ? ((iv - 6) >> 4) : ((iv - 96) >> 2);
            int rec = (varA == 2) ? (16 * m + 6) : (4 * m + 96);
            if (m < 0 || m > 15 || rec != iv) ok = false;
            dm[r] = m & 15;
        }
        vdouble4 p2 = {0.0, 0.0, 0.0, 0.0};
        p2 = __builtin_amdgcn_mfma_f64_16x16x4f64(1.0, (double)lane, p2, 0, 0, 0);
        {
            int iv = (int)p2[0];
            if (iv >= 96 && iv <= 156 && ((iv - 96) & 3) == 0) varB = 1;
            else if (iv >= 6 && iv <= 246 && ((iv - 6) & 15) == 0) varB = 2;
            else ok = false;
        }
#pragma unroll
        for (int r = 0; r < 4; ++r) {
            int iv = (int)p2[r];
            int nn = (varB == 2) ? ((iv - 6) >> 4) : ((iv - 96) >> 2);
            int rec = (varB == 2) ? (16 * nn + 6) : (4 * nn + 96);
            if (nn < 0 || nn > 15 || rec != iv) ok = false;
            dnr[r] = nn & 15;
        }
        // verification with asymmetric operands (exact in f64)
        vdouble4 p3 = {0.0, 0.0, 0.0, 0.0};
        p3 = __builtin_amdgcn_mfma_f64_16x16x4f64(
                (double)lane, (double)(2 * lane + 5), p3, 0, 0, 0);
#pragma unroll
        for (int r = 0; r < 4; ++r) {
            int e = 0;
#pragma unroll
            for (int k = 0; k < 4; ++k) {
                int la = (varA == 2) ? (4 * dm[r] + k)  : (dm[r] + 16 * k);
                int lb = (varB == 2) ? (4 * dnr[r] + k) : (dnr[r] + 16 * k);
                e += la * (2 * lb + 5);
            }
            if ((double)e != p3[r]) ok = false;
        }
    }
    if (tid == 0) okf = 1;
    __syncthreads();
    if (!ok) okf = 0;
    __syncthreads();
    const bool okp = (okf != 0);
    if (!okp) {
#pragma unroll
        for (int r = 0; r < 4; ++r) { dm[r] = kq * 4 + r; dnr[r] = tn; }
    }
    const int am = (varA == 2) ? (lane >> 2) : (lane & 15);
    const int ak = (varA == 2) ? (lane & 3)  : (lane >> 4);
    const int bn = (varB == 2) ? (lane >> 2) : (lane & 15);
    const int bk = (varB == 2) ? (lane & 3)  : (lane >> 4);
    const int aoff = ak * WROW + wv * 16 + am;
    const int boff = bk * XROW + bn;

    vdouble4 acc[4];
#pragma unroll
    for (int tt = 0; tt < 4; ++tt)
#pragma unroll
        for (int i = 0; i < 4; ++i) acc[tt][i] = 0.0;

    for (int ci0 = 0; ci0 < C_IN; ci0 += CI_CH) {
        __syncthreads();
        // stage x tile as f64 (BN+ReLU of previous layer fused, f64; pad = 0)
        for (int e = tid; e < CI_CH * XCOLS; e += 256) {
            int ci  = e / XCOLS;
            int ttx = e - ci * XCOLS;
            int gt  = t0 + ttx - (KS / 2);
            double v = 0.0;
            if (gt >= 0 && gt < T_LEN) {
                float f = x[((size_t)(n * C_IN + ci0 + ci)) * T_LEN + gt];
                if (BN_IN) {
                    double2 s = stats[ci0 + ci];
                    v = fmax(fma((double)f, s.x, s.y), 0.0);
                } else v = (double)f;
            }
            xs[ci * XROW + ttx] = v;
        }
        // stage w tile, converting f32 -> f64 ([k][ci][co] contiguous in co)
        for (int e = tid; e < KS * CI_CH * 64; e += 256) {
            int r  = e >> 6;
            int co = e & 63;
            int k  = r / CI_CH;
            int ci = r - k * CI_CH;
            ws[(k * CI_CH + ci) * WROW + co] =
                (double)wT[((size_t)(k * C_IN + ci0 + ci)) * C_OUT + co0 + co];
        }
        __syncthreads();

        if (okp) {
#pragma unroll
            for (int k = 0; k < KS; ++k) {
#pragma unroll
                for (int c4 = 0; c4 < CI_CH / 4; ++c4) {
                    double av = ws[(k * CI_CH + c4 * 4) * WROW + aoff];
                    const double* xrow = &xs[(c4 * 4) * XROW + k + boff];
#pragma unroll
                    for (int tt = 0; tt < 4; ++tt) {
                        acc[tt] = __builtin_amdgcn_mfma_f64_16x16x4f64(
                            av, xrow[tt * 16], acc[tt], 0, 0, 0);
                    }
                }
            }
        } else {
            // layout-independent f64 fallback (same mapping via dm/dnr)
            for (int k = 0; k < KS; ++k)
                for (int ci = 0; ci < CI_CH; ++ci) {
                    double wr[4], xr[4];
#pragma unroll
                    for (int i = 0; i < 4; ++i)
                        wr[i] = ws[(k * CI_CH + ci) * WROW + wv * 16 + dm[i]];
#pragma unroll
                    for (int tt = 0; tt < 4; ++tt)
                        xr[tt] = xs[ci * XROW + k + tt * 16 + tn];
#pragma unroll
                    for (int tt = 0; tt < 4; ++tt)
#pragma unroll
                        for (int i = 0; i < 4; ++i)
                            acc[tt][i] = fma(wr[i], xr[tt], acc[tt][i]);
                }
        }
    }

    // epilogue: lane reg r holds D[co = co0+wv*16+dm[r]][t = t0+tt*16+dnr[r]]
#pragma unroll
    for (int tt = 0; tt < 4; ++tt) {
#pragma unroll
        for (int r = 0; r < 4; ++r) {
            int co = co0 + wv * 16 + dm[r];
            double bv = (double)bias[co];
            out[((size_t)(n * C_OUT + co)) * T_LEN + t0 + tt * 16 + dnr[r]] =
                (float)(acc[tt][r] + bv);
        }
    }
}

// ---- generic conv1d (f32 acc; fused f64-BN+ReLU on input) ----
template<int C_IN, int C_OUT, int KS, bool BN_IN, typename ACC>
__global__ __launch_bounds__(256) void conv_k(
        const float* __restrict__ x, const float* __restrict__ wT,
        const float* __restrict__ bias, const double2* __restrict__ stats,
        float* __restrict__ out) {
    constexpr int T_TILE = 128;
    constexpr int CI_CH  = (KS == 3) ? 16 : 32;
    constexpr int CI_SH  = (KS == 3) ? 4 : 5;
    constexpr int XCOLS  = T_TILE + KS - 1;
    constexpr int XROW   = (KS == 3) ? 132 : 128;

    __shared__ __align__(16) float xs[CI_CH * XROW];
    __shared__ __align__(16) float ws[KS * CI_CH * 64];

    const int tid = threadIdx.x;
    const int tx  = tid & 15;
    const int ty  = tid >> 4;
    const int n    = blockIdx.x >> 5;
    const int t0   = (blockIdx.x & 31) * T_TILE;
    const int co0  = blockIdx.y * 64;

    ACC acc[4][8];
#pragma unroll
    for (int i = 0; i < 4; ++i)
#pragma unroll
        for (int j = 0; j < 8; ++j) acc[i][j] = (ACC)0;

    for (int ci0 = 0; ci0 < C_IN; ci0 += CI_CH) {
        __syncthreads();
        for (int e = tid; e < CI_CH * XCOLS; e += 256) {
            int ci = e / XCOLS;
            int tt = e - ci * XCOLS;
            int cig = ci0 + ci;
            int gt  = t0 + tt - (KS / 2);
            float v = 0.f;
            if (gt >= 0 && gt < T_LEN) {
                v = x[((size_t)(n * C_IN + cig)) * T_LEN + gt];
                if (BN_IN) {
                    double2 s = stats[cig];
                    double vv = fma((double)v, s.x, s.y);
                    v = (float)fmax(vv, 0.0);
                }
            }
            xs[ci * XROW + tt] = v;
        }
        for (int e = tid; e < KS * CI_CH * 64; e += 256) {
            int co = e & 63;
            int r  = e >> 6;
            int ci = r & (CI_CH - 1);
            int k  = r >> CI_SH;
            int cig = ci0 + ci, cog = co0 + co;
            float v = 0.f;
            if (cog < C_OUT)
                v = wT[((size_t)(k * C_IN + cig)) * C_OUT + cog];
            ws[(k * CI_CH + ci) * 64 + co] = v;
        }
        __syncthreads();

        for (int ci = 0; ci < CI_CH; ++ci) {
            ACC xv[10];
            {
                const float* xr = &xs[ci * XROW + tx * 8];
                float4 a0 = *(const float4*)&xr[0];
                float4 a1 = *(const float4*)&xr[4];
                xv[0] = (ACC)a0.x; xv[1] = (ACC)a0.y; xv[2] = (ACC)a0.z; xv[3] = (ACC)a0.w;
                xv[4] = (ACC)a1.x; xv[5] = (ACC)a1.y; xv[6] = (ACC)a1.z; xv[7] = (ACC)a1.w;
                if (KS == 3) {
                    float2 a2 = *(const float2*)&xr[8];
                    xv[8] = (ACC)a2.x; xv[9] = (ACC)a2.y;
                } else { xv[8] = (ACC)0; xv[9] = (ACC)0; }
            }
            ACC wa[KS][4];
#pragma unroll
            for (int k = 0; k < KS; ++k) {
                float4 wvv = *(const float4*)&ws[(k * CI_CH + ci) * 64 + ty * 4];
                wa[k][0] = (ACC)wvv.x; wa[k][1] = (ACC)wvv.y;
                wa[k][2] = (ACC)wvv.z; wa[k][3] = (ACC)wvv.w;
            }
#pragma unroll
            for (int k = 0; k < KS; ++k)
#pragma unroll
                for (int i = 0; i < 4; ++i)
#pragma unroll
                    for (int j = 0; j < 8; ++j)
                        acc[i][j] = fma(wa[k][i], xv[j + k], acc[i][j]);
        }
    }

    const size_t tb = (size_t)t0 + (size_t)tx * 8;
#pragma unroll
    for (int i = 0; i < 4; ++i) {
        int co = co0 + ty * 4 + i;
        if (co < C_OUT) {
            ACC bv = (ACC)bias[co];
            float* o = out + ((size_t)(n * C_OUT + co)) * T_LEN + tb;
            float r[8];
#pragma unroll
            for (int j = 0; j < 8; ++j) r[j] = (float)(acc[i][j] + bv);
            *(float4*)&o[0] = make_float4(r[0], r[1], r[2], r[3]);
            *(float4*)&o[4] = make_float4(r[4], r[5], r[6], r[7]);
        }
    }
}

// ---- BN stats stage 1: one block per (channel, batch) row -> partial sums ----
__global__ __launch_bounds__(256) void stats1_k(
        const float* __restrict__ y, int C, double2* __restrict__ part) {
    int c = blockIdx.x % C, n = blockIdx.x / C;
    int tid = threadIdx.x;
    const float* p = y + ((size_t)(n * C + c)) * T_LEN;
    double s1 = 0.0, s2 = 0.0;
    for (int t = tid; t < T_LEN; t += 256) {
        double v = p[t];
        s1 += v; s2 += v * v;
    }
    __shared__ double r1[256], r2[256];
    r1[tid] = s1; r2[tid] = s2;
    __syncthreads();
    for (int s = 128; s > 0; s >>= 1) {
        if (tid < s) { r1[tid] += r1[tid + s]; r2[tid] += r2[tid + s]; }
        __syncthreads();
    }
    if (tid == 0) part[(size_t)c * N_B + n] = make_double2(r1[0], r2[0]);
}

// ---- BN stats stage 2: deterministic combine -> (scale, shift) per channel ----
__global__ __launch_bounds__(256) void stats2_k(
        const double2* __restrict__ part, int C, const float* __restrict__ g,
        const float* __restrict__ b, double2* __restrict__ stats) {
    int c = blockIdx.x * 256 + threadIdx.x;
    if (c >= C) return;
    double s1 = 0.0, s2 = 0.0;
    for (int n = 0; n < N_B; ++n) {
        double2 v = part[(size_t)c * N_B + n];
        s1 += v.x; s2 += v.y;
    }
    double m   = s1 / 65536.0;
    double var = s2 / 65536.0 - m * m;
    double sc  = (double)g[c] / sqrt(var + 1e-5);
    stats[c] = make_double2(sc, (double)b[c] - m * sc);
}

// ---- VQ: replicate the reference's f32 d2 formula exactly ----
__global__ __launch_bounds__(256) void vq_k(
        const float* z, const float* __restrict__ cb,
        const float* __restrict__ c2, float* q,
        float* __restrict__ idx_out, double* __restrict__ loss) {
    __shared__ __align__(16) float zs[64 * 68];
    __shared__ __align__(16) float cs[64 * 68];
    __shared__ float  szf[64];
    __shared__ float  redS[64 * 16];
    __shared__ int    redI[64 * 16];
    __shared__ int    idxs[64];
    __shared__ double dred[256];

    const int tid = threadIdx.x;
    const int tx  = tid & 15, ty = tid >> 4;
    const int n   = blockIdx.x >> 6;
    const int t0  = (blockIdx.x & 63) * 64;

    for (int e = tid; e < 4096; e += 256) {
        int t = e & 63, d = e >> 6;
        zs[t * 68 + d] = z[((size_t)(n * 64 + d)) * T_LEN + t0 + t];
    }
    __syncthreads();
    if (tid < 64) {
        double s = 0.0;
        const float* zr = &zs[tid * 68];
        for (int d = 0; d < 64; ++d) { double v = zr[d]; s += v * v; }
        szf[tid] = (float)s;
    }

    float best[4];
    int bidx[4];
#pragma unroll
    for (int i = 0; i < 4; ++i) { best[i] = 3.0e38f; bidx[i] = 1 << 30; }

    for (int ch = 0; ch < 8; ++ch) {
        __syncthreads();
        for (int e = tid; e < 4096; e += 256) {
            int d = e & 63, c = e >> 6;
            cs[c * 68 + d] = cb[((size_t)(ch * 64 + c)) * 64 + d];
        }
        __syncthreads();

        double acc[4][4];
#pragma unroll
        for (int i = 0; i < 4; ++i)
#pragma unroll
            for (int j = 0; j < 4; ++j) acc[i][j] = 0.0;

        for (int d = 0; d < 64; d += 4) {
            float4 zv[4], cv[4];
#pragma unroll
            for (int i = 0; i < 4; ++i)
                zv[i] = *(const float4*)&zs[(tx + 16 * i) * 68 + d];
#pragma unroll
            for (int j = 0; j < 4; ++j)
                cv[j] = *(const float4*)&cs[(ty + 16 * j) * 68 + d];
#pragma unroll
            for (int i = 0; i < 4; ++i)
#pragma unroll
                for (int j = 0; j < 4; ++j) {
                    acc[i][j] = fma((double)zv[i].x, (double)cv[j].x, acc[i][j]);
                    acc[i][j] = fma((double)zv[i].y, (double)cv[j].y, acc[i][j]);
                    acc[i][j] = fma((double)zv[i].z, (double)cv[j].z, acc[i][j]);
                    acc[i][j] = fma((double)zv[i].w, (double)cv[j].w, acc[i][j]);
                }
        }
#pragma unroll
        for (int j = 0; j < 4; ++j) {
            int cg = ch * 64 + ty + 16 * j;
            float cc = c2[cg];
#pragma unroll
            for (int i = 0; i < 4; ++i) {
                float m32 = (float)acc[i][j];
                float A   = szf[tx + 16 * i] + cc;
                float s   = A - 2.0f * m32;
                if (s < best[i] || (s == best[i] && cg < bidx[i])) {
                    best[i] = s; bidx[i] = cg;
                }
            }
        }
    }
#pragma unroll
    for (int i = 0; i < 4; ++i) {
        redS[(tx + 16 * i) * 16 + ty] = best[i];
        redI[(tx + 16 * i) * 16 + ty] = bidx[i];
    }
    __syncthreads();

    if (tid < 64) {
        int t = tid;
        float bs = 3.0e38f; int bi = 1 << 30;
        for (int y2 = 0; y2 < 16; ++y2) {
            float v = redS[t * 16 + y2];
            int vi  = redI[t * 16 + y2];
            if (v < bs || (v == bs && vi < bi)) { bs = v; bi = vi; }
        }
        idxs[t] = bi;
        idx_out[(size_t)n * T_LEN + t0 + t] = (float)bi;
    }
    __syncthreads();

    {
        int g = tid >> 6, t = tid & 63;
        int bi = idxs[t];
        double ls = 0.0;
        for (int dd = 0; dd < 16; ++dd) {
            int d = g * 16 + dd;
            float qv = cb[(size_t)bi * 64 + d];
            float zv = zs[t * 68 + d];
            double df = (double)qv - (double)zv;
            ls += df * df;
            q[((size_t)(n * 64 + d)) * T_LEN + t0 + t] = qv;
        }
        dred[tid] = ls;
    }
    __syncthreads();
    for (int s = 128; s > 0; s >>= 1) {
        if (tid < s) dred[tid] += dred[tid + s];
        __syncthreads();
    }
    if (tid == 0) atomicAdd(loss, dred[0]);
}

__global__ void fin_k(const double* __restrict__ loss, float* __restrict__ out) {
    if (threadIdx.x == 0 && blockIdx.x == 0)
        out[0] = (float)(1.25 * (*loss) / 4194304.0);
}

extern "C" void kernel_launch(void* const* d_in, const int* in_sizes, int n_in,
                              void* d_out, int out_size, void* d_ws, size_t ws_size,
                              hipStream_t stream) {
    const float* x      = (const float*)d_in[0];
    const float* enc_w1 = (const float*)d_in[1];
    const float* enc_b1 = (const float*)d_in[2];
    const float* bn1_g  = (const float*)d_in[3];
    const float* bn1_b  = (const float*)d_in[4];
    const float* enc_w2 = (const float*)d_in[5];
    const float* enc_b2 = (const float*)d_in[6];
    const float* bn2_g  = (const float*)d_in[7];
    const float* bn2_b  = (const float*)d_in[8];
    const float* enc_w3 = (const float*)d_in[9];
    const float* enc_b3 = (const float*)d_in[10];
    const float* cb     = (const float*)d_in[11];
    const float* dec_w1 = (const float*)d_in[12];
    const float* dec_b1 = (const float*)d_in[13];
    const float* dbn1_g = (const float*)d_in[14];
    const float* dbn1_b = (const float*)d_in[15];
    const float* dec_w2 = (const float*)d_in[16];
    const float* dec_b2 = (const float*)d_in[17];
    const float* dbn2_g = (const float*)d_in[18];
    const float* dbn2_b = (const float*)d_in[19];
    const float* dec_w3 = (const float*)d_in[20];
    const float* dec_b3 = (const float*)d_in[21];

    float* wsf   = (float*)d_ws;
    float* outf  = (float*)d_out;
    float* A     = wsf + OFF_A;
    float* Bb    = wsf + OFF_B;
    float* Z     = wsf + OFF_Z;
    double2* st  = (double2*)(wsf + OFF_ST);
    double* lossp = (double*)(wsf + OFF_LOSS);
    double2* partA = (double2*)A;
    double2* partB = (double2*)Bb;

    prep_k<<<1268, 256, 0, stream>>>(enc_w1, enc_w2, enc_w3,
                                     dec_w1, dec_w2, dec_w3, cb, wsf);

    // encoder: f64 MFMA implicit GEMM w/ layout decoder + bit-exact fallback
    mconv_k<80, 128, 3, false><<<dim3(1024, 2), 256, 0, stream>>>(
        x, wsf + OFF_WT1, enc_b1, nullptr, A);
    stats1_k<<<128 * N_B, 256, 0, stream>>>(A, 128, partB);
    stats2_k<<<1, 256, 0, stream>>>(partB, 128, bn1_g, bn1_b, st);
    mconv_k<128, 256, 3, true><<<dim3(1024, 4), 256, 0, stream>>>(
        A, wsf + OFF_WT2, enc_b2, st, Bb);
    stats1_k<<<256 * N_B, 256, 0, stream>>>(Bb, 256, partA);
    stats2_k<<<1, 256, 0, stream>>>(partA, 256, bn2_g, bn2_b, st);
    mconv_k<256, 64, 1, true><<<dim3(1024, 1), 256, 0, stream>>>(
        Bb, wsf + OFF_WT3, enc_b3, st, Z);

    // vector quantizer — f32-formula scores, exact ref grid
    vq_k<<<1024, 256, 0, stream>>>(Z, cb, wsf + OFF_C2, Z,
                                   outf + 5242881, lossp);
    fin_k<<<1, 64, 0, stream>>>(lossp, outf + 5242880);

    // decoder (f32 vector)
    conv_k<64, 256, 3, false, float><<<dim3(512, 4), 256, 0, stream>>>(
        Z, wsf + OFF_WD1, dec_b1, nullptr, Bb);
    stats1_k<<<256 * N_B, 256, 0, stream>>>(Bb, 256, partA);
    stats2_k<<<1, 256, 0, stream>>>(partA, 256, dbn1_g, dbn1_b, st);
    conv_k<256, 128, 3, true, float><<<dim3(512, 2), 256, 0, stream>>>(
        Bb, wsf + OFF_WD2, dec_b2, st, A);
    stats1_k<<<128 * N_B, 256, 0, stream>>>(A, 128, partB);
    stats2_k<<<1, 256, 0, stream>>>(partB, 128, dbn2_g, dbn2_b, st);
    conv_k<128, 80, 3, true, float><<<dim3(512, 2), 256, 0, stream>>>(
        A, wsf + OFF_WD3, dec_b3, st, outf);
}

// Round 8
// 1220.660 us; speedup vs baseline: 1.7905x; 1.5386x over previous
//
#include <hip/hip_runtime.h>
#include <math.h>

#define N_B 16
#define T_LEN 4096

typedef short bf16x8 __attribute__((ext_vector_type(8)));
typedef float f32x4  __attribute__((ext_vector_type(4)));

// ---- workspace layout (float offsets) — r4-proven fit ----
static const size_t OFF_A    = 0;            // 16*128*4096
static const size_t OFF_B    = 8388608;      // 16*256*4096
static const size_t OFF_Z    = 25165824;     // 16*64*4096
static const size_t OFF_WT1  = 29360128;
static const size_t OFF_WT2  = 29390848;
static const size_t OFF_WT3  = 29489152;
static const size_t OFF_WD1  = 29505536;
static const size_t OFF_WD2  = 29554688;
static const size_t OFF_WD3  = 29652992;
static const size_t OFF_C2   = 29683712;
static const size_t OFF_ST   = 29684736;
static const size_t OFF_LOSS = 29685760;

__device__ inline unsigned short f2bf(float f) {
    unsigned u = __float_as_uint(f);
    unsigned r = (u + 0x7FFFu + ((u >> 16) & 1u)) >> 16;
    return (unsigned short)r;
}
__device__ inline float bf2f(unsigned short h) {
    return __uint_as_float(((unsigned)h) << 16);
}

// ---- weight transpose helper: w[CO][CI][KS] -> wT[KS][CI][CO] (f32) ----
template<int C_OUT, int C_IN, int KS>
__device__ inline void tw(const float* __restrict__ w, float* __restrict__ wT, int e) {
    int co  = e / (C_IN * KS);
    int rem = e - co * (C_IN * KS);
    int ci  = rem / KS;
    int k   = rem - ci * KS;
    wT[(k * C_IN + ci) * C_OUT + co] = w[e];
}

__global__ __launch_bounds__(256) void prep_k(
        const float* __restrict__ w1, const float* __restrict__ w2,
        const float* __restrict__ w3, const float* __restrict__ wd1,
        const float* __restrict__ wd2, const float* __restrict__ wd3,
        const float* __restrict__ cb, float* wsf) {
    int e = blockIdx.x * 256 + threadIdx.x;
    if (e < 30720)        tw<128,  80, 3>(w1,  wsf + OFF_WT1, e);
    else if (e < 129024)  tw<256, 128, 3>(w2,  wsf + OFF_WT2, e - 30720);
    else if (e < 145408)  tw< 64, 256, 1>(w3,  wsf + OFF_WT3, e - 129024);
    else if (e < 194560)  tw<256,  64, 3>(wd1, wsf + OFF_WD1, e - 145408);
    else if (e < 292864)  tw<128, 256, 3>(wd2, wsf + OFF_WD2, e - 194560);
    else if (e < 323584)  tw< 80, 128, 3>(wd3, wsf + OFF_WD3, e - 292864);
    else if (e < 324096) {
        int c = e - 323584;
        const float* p = cb + (size_t)c * 64;
        double s = 0.0;
        for (int d = 0; d < 64; ++d) { double v = p[d]; s += v * v; }
        wsf[OFF_C2 + c] = (float)s;
    } else if (e == 324096) {
        *(double*)(wsf + OFF_LOSS) = 0.0;
    }
}

// ---- encoder conv1d: f64-vector accumulation (r4-proven, bit-exact path) ----
template<int C_IN, int C_OUT, int KS, bool BN_IN, typename ACC>
__global__ __launch_bounds__(256) void conv_k(
        const float* __restrict__ x, const float* __restrict__ wT,
        const float* __restrict__ bias, const double2* __restrict__ stats,
        float* __restrict__ out) {
    constexpr int T_TILE = 128;
    constexpr int CI_CH  = (KS == 3) ? 16 : 32;
    constexpr int CI_SH  = (KS == 3) ? 4 : 5;
    constexpr int XCOLS  = T_TILE + KS - 1;
    constexpr int XROW   = (KS == 3) ? 132 : 128;

    __shared__ __align__(16) float xs[CI_CH * XROW];
    __shared__ __align__(16) float ws[KS * CI_CH * 64];

    const int tid = threadIdx.x;
    const int tx  = tid & 15;
    const int ty  = tid >> 4;
    const int n    = blockIdx.x >> 5;
    const int t0   = (blockIdx.x & 31) * T_TILE;
    const int co0  = blockIdx.y * 64;

    ACC acc[4][8];
#pragma unroll
    for (int i = 0; i < 4; ++i)
#pragma unroll
        for (int j = 0; j < 8; ++j) acc[i][j] = (ACC)0;

    for (int ci0 = 0; ci0 < C_IN; ci0 += CI_CH) {
        __syncthreads();
        for (int e = tid; e < CI_CH * XCOLS; e += 256) {
            int ci = e / XCOLS;
            int tt = e - ci * XCOLS;
            int cig = ci0 + ci;
            int gt  = t0 + tt - (KS / 2);
            float v = 0.f;
            if (gt >= 0 && gt < T_LEN) {
                v = x[((size_t)(n * C_IN + cig)) * T_LEN + gt];
                if (BN_IN) {
                    double2 s = stats[cig];
                    double vv = fma((double)v, s.x, s.y);
                    v = (float)fmax(vv, 0.0);
                }
            }
            xs[ci * XROW + tt] = v;
        }
        for (int e = tid; e < KS * CI_CH * 64; e += 256) {
            int co = e & 63;
            int r  = e >> 6;
            int ci = r & (CI_CH - 1);
            int k  = r >> CI_SH;
            int cig = ci0 + ci, cog = co0 + co;
            float v = 0.f;
            if (cog < C_OUT)
                v = wT[((size_t)(k * C_IN + cig)) * C_OUT + cog];
            ws[(k * CI_CH + ci) * 64 + co] = v;
        }
        __syncthreads();

        for (int ci = 0; ci < CI_CH; ++ci) {
            ACC xv[10];
            {
                const float* xr = &xs[ci * XROW + tx * 8];
                float4 a0 = *(const float4*)&xr[0];
                float4 a1 = *(const float4*)&xr[4];
                xv[0] = (ACC)a0.x; xv[1] = (ACC)a0.y; xv[2] = (ACC)a0.z; xv[3] = (ACC)a0.w;
                xv[4] = (ACC)a1.x; xv[5] = (ACC)a1.y; xv[6] = (ACC)a1.z; xv[7] = (ACC)a1.w;
                if (KS == 3) {
                    float2 a2 = *(const float2*)&xr[8];
                    xv[8] = (ACC)a2.x; xv[9] = (ACC)a2.y;
                } else { xv[8] = (ACC)0; xv[9] = (ACC)0; }
            }
            ACC wa[KS][4];
#pragma unroll
            for (int k = 0; k < KS; ++k) {
                float4 wvv = *(const float4*)&ws[(k * CI_CH + ci) * 64 + ty * 4];
                wa[k][0] = (ACC)wvv.x; wa[k][1] = (ACC)wvv.y;
                wa[k][2] = (ACC)wvv.z; wa[k][3] = (ACC)wvv.w;
            }
#pragma unroll
            for (int k = 0; k < KS; ++k)
#pragma unroll
                for (int i = 0; i < 4; ++i)
#pragma unroll
                    for (int j = 0; j < 8; ++j)
                        acc[i][j] = fma(wa[k][i], xv[j + k], acc[i][j]);
        }
    }

    const size_t tb = (size_t)t0 + (size_t)tx * 8;
#pragma unroll
    for (int i = 0; i < 4; ++i) {
        int co = co0 + ty * 4 + i;
        if (co < C_OUT) {
            ACC bv = (ACC)bias[co];
            float* o = out + ((size_t)(n * C_OUT + co)) * T_LEN + tb;
            float r[8];
#pragma unroll
            for (int j = 0; j < 8; ++j) r[j] = (float)(acc[i][j] + bv);
            *(float4*)&o[0] = make_float4(r[0], r[1], r[2], r[3]);
            *(float4*)&o[4] = make_float4(r[4], r[5], r[6], r[7]);
        }
    }
}

// ---- decoder conv1d via split-bf16 MFMA (3-product Markidis, f32 acc) ----
// GEMM M=co, N=t, K=ci (per k-tap). Block: 64co x 64t, 4 waves (wave=co strip).
// Assumed gfx950 16x16x32 bf16 maps (m89/m120-verified): A[m=lane&15][k=q*8+j],
// B[k=q*8+j][n=lane&15], D[m=q*4+r][n=lane&15]. Integer probe verifies; on
// mismatch a plain-f32 VALU path computes from the same LDS tiles.
template<int C_IN, int C_OUT, bool BN_IN>
__global__ __launch_bounds__(256) void mbconv_k(
        const float* __restrict__ x, const float* __restrict__ wT,
        const float* __restrict__ bias, const double2* __restrict__ stats,
        float* __restrict__ out) {
    constexpr int CI_CH = 32;
    constexpr int RS    = 72;       // row stride in shorts (144B, 16B-aligned)
    constexpr int LO    = 40;       // lo-block offset within row (80B)

    __shared__ __align__(16) short xs[66 * RS];     // t rows (t0-1..t0+64)
    __shared__ __align__(16) short ws[192 * RS];    // (k*64+co) rows
    __shared__ int okf;

    const int tid  = threadIdx.x;
    const int lane = tid & 63;
    const int wv   = tid >> 6;
    const int ln   = lane & 15;
    const int q    = lane >> 4;

    const int n   = blockIdx.x >> 6;
    const int t0  = (blockIdx.x & 63) * 64;
    const int co0 = blockIdx.y * 64;

    // ---- layout verify probe (exact integers in bf16/f32) ----
    bool ok = true;
    {
        bf16x8 pa, pb;
#pragma unroll
        for (int j = 0; j < 8; ++j) {
            int kk = q * 8 + j;
            pa[j] = (short)f2bf((float)(ln + 2 * kk));
            pb[j] = (short)f2bf((float)(ln + 3 * kk));
        }
        f32x4 pd = {0.f, 0.f, 0.f, 0.f};
        pd = __builtin_amdgcn_mfma_f32_16x16x32_bf16(pa, pb, pd, 0, 0, 0);
#pragma unroll
        for (int r = 0; r < 4; ++r) {
            int m = q * 4 + r;
            float e = (float)(32 * m * ln + 1488 * m + 992 * ln + 62496);
            if (pd[r] != e) ok = false;
        }
    }
    if (tid == 0) okf = 1;
    __syncthreads();
    if (!ok) okf = 0;
    __syncthreads();
    const bool okp = (okf != 0);

    f32x4 acc[4];
#pragma unroll
    for (int tt = 0; tt < 4; ++tt)
#pragma unroll
        for (int i = 0; i < 4; ++i) acc[tt][i] = 0.f;

    for (int ci0 = 0; ci0 < C_IN; ci0 += CI_CH) {
        __syncthreads();
        // stage x: rows trow=0..65 (t = t0-1+trow), cols ci (hi) / LO+ci (lo)
        for (int e = tid; e < CI_CH * 66; e += 256) {
            int ci   = e / 66;
            int trow = e - ci * 66;
            int gt   = t0 - 1 + trow;
            float v  = 0.f;
            if (gt >= 0 && gt < T_LEN) {
                v = x[((size_t)(n * C_IN + ci0 + ci)) * T_LEN + gt];
                if (BN_IN) {
                    double2 s = stats[ci0 + ci];
                    v = (float)fmax(fma((double)v, s.x, s.y), 0.0);
                }
            }
            unsigned short h = f2bf(v);
            unsigned short l = f2bf(v - bf2f(h));
            xs[trow * RS + ci]      = (short)h;
            xs[trow * RS + LO + ci] = (short)l;
        }
        // stage w: rows (k*64+co), cols ci / LO+ci; zero-pad co >= C_OUT
        for (int e = tid; e < 3 * CI_CH * 64; e += 256) {
            int co = e & 63;
            int rr = e >> 6;           // k*32+ci
            int k  = rr >> 5;
            int ci = rr & 31;
            float v = 0.f;
            if (co0 + co < C_OUT)
                v = wT[((size_t)(k * C_IN + ci0 + ci)) * C_OUT + co0 + co];
            unsigned short h = f2bf(v);
            unsigned short l = f2bf(v - bf2f(h));
            ws[(k * 64 + co) * RS + ci]      = (short)h;
            ws[(k * 64 + co) * RS + LO + ci] = (short)l;
        }
        __syncthreads();

        if (okp) {
#pragma unroll
            for (int k = 0; k < 3; ++k) {
                const short* wr = &ws[(k * 64 + wv * 16 + ln) * RS + q * 8];
                bf16x8 ah = *(const bf16x8*)&wr[0];
                bf16x8 al = *(const bf16x8*)&wr[LO];
#pragma unroll
                for (int tt = 0; tt < 4; ++tt) {
                    const short* xr = &xs[(tt * 16 + ln + k) * RS + q * 8];
                    bf16x8 bh = *(const bf16x8*)&xr[0];
                    bf16x8 bl = *(const bf16x8*)&xr[LO];
                    acc[tt] = __builtin_amdgcn_mfma_f32_16x16x32_bf16(ah, bh, acc[tt], 0, 0, 0);
                    acc[tt] = __builtin_amdgcn_mfma_f32_16x16x32_bf16(ah, bl, acc[tt], 0, 0, 0);
                    acc[tt] = __builtin_amdgcn_mfma_f32_16x16x32_bf16(al, bh, acc[tt], 0, 0, 0);
                }
            }
        } else {
            // plain-f32 fallback from same tiles; acc matches D-map (m=q*4+r)
            for (int k = 0; k < 3; ++k)
                for (int ci = 0; ci < CI_CH; ++ci) {
                    float wr[4], xv[4];
#pragma unroll
                    for (int r = 0; r < 4; ++r) {
                        const short* p = &ws[(k * 64 + wv * 16 + q * 4 + r) * RS];
                        wr[r] = bf2f((unsigned short)p[ci]) + bf2f((unsigned short)p[LO + ci]);
                    }
#pragma unroll
                    for (int tt = 0; tt < 4; ++tt) {
                        const short* p = &xs[(tt * 16 + ln + k) * RS];
                        xv[tt] = bf2f((unsigned short)p[ci]) + bf2f((unsigned short)p[LO + ci]);
                    }
#pragma unroll
                    for (int tt = 0; tt < 4; ++tt)
#pragma unroll
                        for (int r = 0; r < 4; ++r)
                            acc[tt][r] = fmaf(wr[r], xv[tt], acc[tt][r]);
                }
        }
    }

    // epilogue: lane reg r -> D[co = co0+wv*16+q*4+r][t = t0+tt*16+ln]
#pragma unroll
    for (int tt = 0; tt < 4; ++tt) {
#pragma unroll
        for (int r = 0; r < 4; ++r) {
            int co = co0 + wv * 16 + q * 4 + r;
            if (co < C_OUT)
                out[((size_t)(n * C_OUT + co)) * T_LEN + t0 + tt * 16 + ln] =
                    acc[tt][r] + bias[co];
        }
    }
}

// ---- BN stats stage 1 ----
__global__ __launch_bounds__(256) void stats1_k(
        const float* __restrict__ y, int C, double2* __restrict__ part) {
    int c = blockIdx.x % C, n = blockIdx.x / C;
    int tid = threadIdx.x;
    const float* p = y + ((size_t)(n * C + c)) * T_LEN;
    double s1 = 0.0, s2 = 0.0;
    for (int t = tid; t < T_LEN; t += 256) {
        double v = p[t];
        s1 += v; s2 += v * v;
    }
    __shared__ double r1[256], r2[256];
    r1[tid] = s1; r2[tid] = s2;
    __syncthreads();
    for (int s = 128; s > 0; s >>= 1) {
        if (tid < s) { r1[tid] += r1[tid + s]; r2[tid] += r2[tid + s]; }
        __syncthreads();
    }
    if (tid == 0) part[(size_t)c * N_B + n] = make_double2(r1[0], r2[0]);
}

// ---- BN stats stage 2 ----
__global__ __launch_bounds__(256) void stats2_k(
        const double2* __restrict__ part, int C, const float* __restrict__ g,
        const float* __restrict__ b, double2* __restrict__ stats) {
    int c = blockIdx.x * 256 + threadIdx.x;
    if (c >= C) return;
    double s1 = 0.0, s2 = 0.0;
    for (int n = 0; n < N_B; ++n) {
        double2 v = part[(size_t)c * N_B + n];
        s1 += v.x; s2 += v.y;
    }
    double m   = s1 / 65536.0;
    double var = s2 / 65536.0 - m * m;
    double sc  = (double)g[c] / sqrt(var + 1e-5);
    stats[c] = make_double2(sc, (double)b[c] - m * sc);
}

// ---- VQ: replicate the reference's f32 d2 formula exactly ----
__global__ __launch_bounds__(256) void vq_k(
        const float* z, const float* __restrict__ cb,
        const float* __restrict__ c2, float* q,
        float* __restrict__ idx_out, double* __restrict__ loss) {
    __shared__ __align__(16) float zs[64 * 68];
    __shared__ __align__(16) float cs[64 * 68];
    __shared__ float  szf[64];
    __shared__ float  redS[64 * 16];
    __shared__ int    redI[64 * 16];
    __shared__ int    idxs[64];
    __shared__ double dred[256];

    const int tid = threadIdx.x;
    const int tx  = tid & 15, ty = tid >> 4;
    const int n   = blockIdx.x >> 6;
    const int t0  = (blockIdx.x & 63) * 64;

    for (int e = tid; e < 4096; e += 256) {
        int t = e & 63, d = e >> 6;
        zs[t * 68 + d] = z[((size_t)(n * 64 + d)) * T_LEN + t0 + t];
    }
    __syncthreads();
    if (tid < 64) {
        double s = 0.0;
        const float* zr = &zs[tid * 68];
        for (int d = 0; d < 64; ++d) { double v = zr[d]; s += v * v; }
        szf[tid] = (float)s;
    }

    float best[4];
    int bidx[4];
#pragma unroll
    for (int i = 0; i < 4; ++i) { best[i] = 3.0e38f; bidx[i] = 1 << 30; }

    for (int ch = 0; ch < 8; ++ch) {
        __syncthreads();
        for (int e = tid; e < 4096; e += 256) {
            int d = e & 63, c = e >> 6;
            cs[c * 68 + d] = cb[((size_t)(ch * 64 + c)) * 64 + d];
        }
        __syncthreads();

        double acc[4][4];
#pragma unroll
        for (int i = 0; i < 4; ++i)
#pragma unroll
            for (int j = 0; j < 4; ++j) acc[i][j] = 0.0;

        for (int d = 0; d < 64; d += 4) {
            float4 zv[4], cv[4];
#pragma unroll
            for (int i = 0; i < 4; ++i)
                zv[i] = *(const float4*)&zs[(tx + 16 * i) * 68 + d];
#pragma unroll
            for (int j = 0; j < 4; ++j)
                cv[j] = *(const float4*)&cs[(ty + 16 * j) * 68 + d];
#pragma unroll
            for (int i = 0; i < 4; ++i)
#pragma unroll
                for (int j = 0; j < 4; ++j) {
                    acc[i][j] = fma((double)zv[i].x, (double)cv[j].x, acc[i][j]);
                    acc[i][j] = fma((double)zv[i].y, (double)cv[j].y, acc[i][j]);
                    acc[i][j] = fma((double)zv[i].z, (double)cv[j].z, acc[i][j]);
                    acc[i][j] = fma((double)zv[i].w, (double)cv[j].w, acc[i][j]);
                }
        }
#pragma unroll
        for (int j = 0; j < 4; ++j) {
            int cg = ch * 64 + ty + 16 * j;
            float cc = c2[cg];
#pragma unroll
            for (int i = 0; i < 4; ++i) {
                float m32 = (float)acc[i][j];
                float A   = szf[tx + 16 * i] + cc;
                float s   = A - 2.0f * m32;
                if (s < best[i] || (s == best[i] && cg < bidx[i])) {
                    best[i] = s; bidx[i] = cg;
                }
            }
        }
    }
#pragma unroll
    for (int i = 0; i < 4; ++i) {
        redS[(tx + 16 * i) * 16 + ty] = best[i];
        redI[(tx + 16 * i) * 16 + ty] = bidx[i];
    }
    __syncthreads();

    if (tid < 64) {
        int t = tid;
        float bs = 3.0e38f; int bi = 1 << 30;
        for (int y2 = 0; y2 < 16; ++y2) {
            float v = redS[t * 16 + y2];
            int vi  = redI[t * 16 + y2];
            if (v < bs || (v == bs && vi < bi)) { bs = v; bi = vi; }
        }
        idxs[t] = bi;
        idx_out[(size_t)n * T_LEN + t0 + t] = (float)bi;
    }
    __syncthreads();

    {
        int g = tid >> 6, t = tid & 63;
        int bi = idxs[t];
        double ls = 0.0;
        for (int dd = 0; dd < 16; ++dd) {
            int d = g * 16 + dd;
            float qv = cb[(size_t)bi * 64 + d];
            float zv = zs[t * 68 + d];
            double df = (double)qv - (double)zv;
            ls += df * df;
            q[((size_t)(n * 64 + d)) * T_LEN + t0 + t] = qv;
        }
        dred[tid] = ls;
    }
    __syncthreads();
    for (int s = 128; s > 0; s >>= 1) {
        if (tid < s) dred[tid] += dred[tid + s];
        __syncthreads();
    }
    if (tid == 0) atomicAdd(loss, dred[0]);
}

__global__ void fin_k(const double* __restrict__ loss, float* __restrict__ out) {
    if (threadIdx.x == 0 && blockIdx.x == 0)
        out[0] = (float)(1.25 * (*loss) / 4194304.0);
}

extern "C" void kernel_launch(void* const* d_in, const int* in_sizes, int n_in,
                              void* d_out, int out_size, void* d_ws, size_t ws_size,
                              hipStream_t stream) {
    const float* x      = (const float*)d_in[0];
    const float* enc_w1 = (const float*)d_in[1];
    const float* enc_b1 = (const float*)d_in[2];
    const float* bn1_g  = (const float*)d_in[3];
    const float* bn1_b  = (const float*)d_in[4];
    const float* enc_w2 = (const float*)d_in[5];
    const float* enc_b2 = (const float*)d_in[6];
    const float* bn2_g  = (const float*)d_in[7];
    const float* bn2_b  = (const float*)d_in[8];
    const float* enc_w3 = (const float*)d_in[9];
    const float* enc_b3 = (const float*)d_in[10];
    const float* cb     = (const float*)d_in[11];
    const float* dec_w1 = (const float*)d_in[12];
    const float* dec_b1 = (const float*)d_in[13];
    const float* dbn1_g = (const float*)d_in[14];
    const float* dbn1_b = (const float*)d_in[15];
    const float* dec_w2 = (const float*)d_in[16];
    const float* dec_b2 = (const float*)d_in[17];
    const float* dbn2_g = (const float*)d_in[18];
    const float* dbn2_b = (const float*)d_in[19];
    const float* dec_w3 = (const float*)d_in[20];
    const float* dec_b3 = (const float*)d_in[21];

    float* wsf   = (float*)d_ws;
    float* outf  = (float*)d_out;
    float* A     = wsf + OFF_A;
    float* Bb    = wsf + OFF_B;
    float* Z     = wsf + OFF_Z;
    double2* st  = (double2*)(wsf + OFF_ST);
    double* lossp = (double*)(wsf + OFF_LOSS);
    double2* partA = (double2*)A;
    double2* partB = (double2*)Bb;

    prep_k<<<1268, 256, 0, stream>>>(enc_w1, enc_w2, enc_w3,
                                     dec_w1, dec_w2, dec_w3, cb, wsf);

    // encoder: f64-vector (bit-exact, r4-proven)
    conv_k<80, 128, 3, false, double><<<dim3(512, 2), 256, 0, stream>>>(
        x, wsf + OFF_WT1, enc_b1, nullptr, A);
    stats1_k<<<128 * N_B, 256, 0, stream>>>(A, 128, partB);
    stats2_k<<<1, 256, 0, stream>>>(partB, 128, bn1_g, bn1_b, st);
    conv_k<128, 256, 3, true, double><<<dim3(512, 4), 256, 0, stream>>>(
        A, wsf + OFF_WT2, enc_b2, st, Bb);
    stats1_k<<<256 * N_B, 256, 0, stream>>>(Bb, 256, partA);
    stats2_k<<<1, 256, 0, stream>>>(partA, 256, bn2_g, bn2_b, st);
    conv_k<256, 64, 1, true, double><<<dim3(512, 1), 256, 0, stream>>>(
        Bb, wsf + OFF_WT3, enc_b3, st, Z);

    // vector quantizer — f32-formula scores, exact ref grid
    vq_k<<<1024, 256, 0, stream>>>(Z, cb, wsf + OFF_C2, Z,
                                   outf + 5242881, lossp);
    fin_k<<<1, 64, 0, stream>>>(lossp, outf + 5242880);

    // decoder: split-bf16 MFMA (probe-verified, f32-fallback-protected)
    mbconv_k<64, 256, false><<<dim3(1024, 4), 256, 0, stream>>>(
        Z, wsf + OFF_WD1, dec_b1, nullptr, Bb);
    stats1_k<<<256 * N_B, 256, 0, stream>>>(Bb, 256, partA);
    stats2_k<<<1, 256, 0, stream>>>(partA, 256, dbn1_g, dbn1_b, st);
    mbconv_k<256, 128, true><<<dim3(1024, 2), 256, 0, stream>>>(
        Bb, wsf + OFF_WD2, dec_b2, st, A);
    stats1_k<<<128 * N_B, 256, 0, stream>>>(A, 128, partB);
    stats2_k<<<1, 256, 0, stream>>>(partB, 128, dbn2_g, dbn2_b, st);
    mbconv_k<128, 80, true><<<dim3(1024, 2), 256, 0, stream>>>(
        A, wsf + OFF_WD3, dec_b3, st, outf);
}